// Round 6
// baseline (6073.599 us; speedup 1.0000x reference)
//
#include <hip/hip_runtime.h>
#include <math.h>

#define NTAU 82
#define TMIN 28
#define S_TOT 5617
#define TF 6000
#define BATCH 4
#define WMAX 28
#define AP 84            // A/fb row pitch: 82 + 2 pad; rows 336B = 21*16B aligned
#define NTHREADS 1024
#define NCHUNK 215
#define CHUNK_F (WMAX * AP)   // 2352 floats per chunk of A-history

// ws layout (float offsets)
#define TRANS_OFF 0            // 82*82
#define BLP_OFF   8192         // 4*6000
#define NBLP_OFF  32768        // 4*6000
#define AH_OFF    57344        // 4 * 215 * 2352 (chunk-major A history)

__device__ __forceinline__ int first_of(int b) { return b * (55 + b) / 2; }
__device__ __forceinline__ int nf_of(int b)    { return b * (b - 1) / 2; }

__device__ __forceinline__ float logsig(float x) {
    return -(fmaxf(-x, 0.0f) + log1pf(expf(-fabsf(x))));
}

// ---------------- setup kernel 1: trans_log in fp64, cast to fp32 -------------
__global__ void k_trans(float* __restrict__ ws) {
    int i = blockIdx.x;
    int j = threadIdx.x;
    __shared__ double sh[128];
    double raw = 0.0, e = 0.0;
    double ti = 28.0 + (double)i;
    if (j < NTAU) {
        double tj = 28.0 + (double)j;
        raw = -100.0 * fabs(tj / ti - 1.0);
        e = exp(raw);
    }
    sh[j] = e;
    __syncthreads();
    for (int st = 64; st > 0; st >>= 1) {
        if (j < st) sh[j] += sh[j + st];
        __syncthreads();
    }
    double lse = log(sh[0]);
    if (j < NTAU) ws[TRANS_OFF + i * NTAU + j] = (float)(raw - lse);
}

// ---------------- setup kernel 2: emissions + zero output ---------------------
__global__ void k_emis(const float* __restrict__ logit, float* __restrict__ ws,
                       float* __restrict__ out) {
    int idx = blockIdx.x * blockDim.x + threadIdx.x;
    if (idx < BATCH * TF) {
        float x = logit[idx];
        ws[BLP_OFF + idx]  = logsig(x);
        ws[NBLP_OFF + idx] = logsig(-x);
        out[idx] = 0.0f;
    }
}

// ---------------- main kernel: chunked Viterbi + backtrace --------------------
__global__ __attribute__((amdgpu_flat_work_group_size(NTHREADS, NTHREADS),
                          amdgpu_waves_per_eu(4, 4)))
void k_viterbi(const float* __restrict__ logit,
               const float* __restrict__ transg,
               const float* __restrict__ blp_all,
               const float* __restrict__ nblp_all,
               float* __restrict__ Ah_all,
               float* __restrict__ out) {
    const int tid = threadIdx.x;
    const int b = blockIdx.x;

    const float* blp  = blp_all  + b * TF;
    const float* nblp = nblp_all + b * TF;
    float* Ah = Ah_all + (size_t)b * (NCHUNK * CHUNK_F);

    __shared__ float V[5632];                       // slot values, idx = first_of(b)+r
    __shared__ __align__(16) float A_lds[CHUNK_F];  // captures (prev_last) [tt][i]
    __shared__ __align__(16) float fb[CHUNK_F];     // from_beat [tt][j]
    __shared__ __align__(16) float win_nb[4][WMAX]; // quad-buffered emission windows
    __shared__ __align__(16) float win_b[4][WMAX];
    __shared__ float wv[16];
    __shared__ int   wi[16];

    // ---- ph2 mapping (ONLY change vs r3): quad lanes = iseg; jg = j-TRIPLE; ----
    // tg = tl-group (9). Tasks/thread 4.67 -> 3.11 => ~35% fewer A-row b128 reads.
    const int iseg = tid & 3;
    const int jg   = (tid >> 2) % 28;     // j0 = 3*jg (0..81)
    const int tg   = tid / 112;           // 0..8 (quads never straddle: 112%4==0)
    const bool p2act = (tid < 1008);      // 4*28*9 = 1008
    const int i0 = iseg * 20;             // 20/20/20/22 split; 16B-aligned offsets
    const int j0 = jg * 3;

    // trans columns in scalar registers (same codegen style as r3's proven loop)
    float tr0[22], tr1[22], tr2c[22];
#pragma unroll
    for (int k = 0; k < 22; ++k) { tr0[k] = -1.0e30f; tr1[k] = -1.0e30f; tr2c[k] = -1.0e30f; }
    if (p2act) {
        const int icnt = (iseg == 3) ? 22 : 20;
#pragma unroll
        for (int k = 0; k < 22; ++k) {
            if (k < icnt) {
                const int row = (i0 + k) * NTAU;
                tr0[k] = transg[row + j0];
                if (j0 + 1 < NTAU) tr1[k]  = transg[row + j0 + 1];
                if (j0 + 2 < NTAU) tr2c[k] = transg[row + j0 + 2];
            }
        }
    }

    // ---- reset-slot mapping (r3-proven): thread = (off o, base s); blocks s,s+36,s+72
    const bool ract = (tid < 1008);
    const int ro = ract ? (tid / 36) : 27;
    const int rs = tid % 36;
    const bool rv2 = ract && (rs < 10);
    const int rb0 = rs, rb1 = rs + 36, rb2 = rs + 72;
    const int rt0 = TMIN + rb0, rt1 = TMIN + rb1, rt2 = TMIN + (rv2 ? rb2 : 0);
    const int rf0 = first_of(rb0), rf1 = first_of(rb1), rf2 = rv2 ? first_of(rb2) : 0;
    int rr0 = ro, rr1 = ro, rr2 = ro;

    // ---- non-reset mapping (r3-proven): flat f over 3321, 4 static slots ----
    int nrR[4], nrFo[4], nrTau[4];
    bool nrV[4];
#pragma unroll
    for (int q = 0; q < 4; ++q) {
        const int f = tid + q * NTHREADS;
        nrV[q] = (f < 3321);
        nrR[q] = 0; nrFo[q] = 0; nrTau[q] = 109;
        if (nrV[q]) {
            int lo = 1, hi = NTAU - 1;
            while (lo < hi) { int mid = (lo + hi + 1) >> 1;
                              if (nf_of(mid) <= f) lo = mid; else hi = mid - 1; }
            const int m = f - nf_of(lo);
            nrR[q]   = TMIN + m;
            nrFo[q]  = first_of(lo);
            nrTau[q] = TMIN + lo;
        }
    }

    // ---- V init ----
    const float logS = (float)log((double)S_TOT);
    const float b0 = blp[0], n0 = nblp[0];
    for (int g = tid; g < S_TOT; g += NTHREADS) {
        int lo = 0, hi = NTAU - 1;
        while (lo < hi) { int mid = (lo + hi + 1) >> 1;
                          if (first_of(mid) <= g) lo = mid; else hi = mid - 1; }
        const int tau = TMIN + lo;
        const int r = g - first_of(lo);
        V[g] = ((r == tau - 1) ? b0 : n0) - logS;
    }

    auto winload = [&](int cc) {
        if (cc < NCHUNK && tid < WMAX) {
            int gt = 1 + cc * WMAX + tid;
            win_nb[cc & 3][tid] = (gt < TF) ? nblp[gt] : 0.0f;
            win_b [cc & 3][tid] = (gt < TF) ? blp[gt]  : 0.0f;
        }
    };
    winload(0);
    winload(1);
    __syncthreads();

    float cv0 = 0.0f, cv1 = 0.0f, cv2 = 0.0f;
    for (int c = 0; c < NCHUNK; ++c) {
        const int buf = c & 3;

        // ---- window to registers (b128 loads; constant-index use only) ----
        float nbr[WMAX];
        {
            const float4* wn4 = (const float4*)&win_nb[buf][0];
#pragma unroll
            for (int qq = 0; qq < 7; ++qq) {
                float4 t4 = wn4[qq];
                nbr[4*qq+0] = t4.x; nbr[4*qq+1] = t4.y; nbr[4*qq+2] = t4.z; nbr[4*qq+3] = t4.w;
            }
        }

        // ---- prefix: capture C = V + nb[0..ro-1] (exact sequential; r3 form) ----
        cv0 = ract ? V[rf0 + rr0] : 0.0f;
        cv1 = ract ? V[rf1 + rr1] : 0.0f;
        cv2 = rv2  ? V[rf2 + rr2] : 0.0f;
        for (int tt = 0; tt < ro; ++tt) {
            const float w = win_nb[buf][tt];
            cv0 += w; cv1 += w; cv2 += w;
        }
        if (ract) {
            A_lds[ro * AP + rb0] = cv0;
            A_lds[ro * AP + rb1] = cv1;
            if (rv2) A_lds[ro * AP + rb2] = cv2;
        }
        winload(c + 2);
        __syncthreads();   // B1: captures ready

        // ---- A history to global (coalesced float4) ----
        if (tid < CHUNK_F / 4) {
            float4 v4 = ((const float4*)A_lds)[tid];
            ((float4*)(Ah + (size_t)c * CHUNK_F))[tid] = v4;
        }

        // ---- ph2: from_beat max-plus; A rows b128; 4-lane shuffle reduce ----
        if (p2act) {
#pragma unroll
            for (int u = 0; u < 4; ++u) {
                const int tl = tg + 9 * u;
                if (tl < WMAX) {
                    const float4* ar4 = (const float4*)&A_lds[tl * AP + i0];
                    const float4 a0 = ar4[0], a1 = ar4[1], a2 = ar4[2],
                                 a3 = ar4[3], a4 = ar4[4];
                    float m0 = -INFINITY, m1 = -INFINITY, m2 = -INFINITY;
#define PH2_STEP(av, k) \
    m0 = fmaxf(m0, (av) + tr0[k]); \
    m1 = fmaxf(m1, (av) + tr1[k]); \
    m2 = fmaxf(m2, (av) + tr2c[k]);
                    PH2_STEP(a0.x, 0)  PH2_STEP(a0.y, 1)  PH2_STEP(a0.z, 2)  PH2_STEP(a0.w, 3)
                    PH2_STEP(a1.x, 4)  PH2_STEP(a1.y, 5)  PH2_STEP(a1.z, 6)  PH2_STEP(a1.w, 7)
                    PH2_STEP(a2.x, 8)  PH2_STEP(a2.y, 9)  PH2_STEP(a2.z, 10) PH2_STEP(a2.w, 11)
                    PH2_STEP(a3.x, 12) PH2_STEP(a3.y, 13) PH2_STEP(a3.z, 14) PH2_STEP(a3.w, 15)
                    PH2_STEP(a4.x, 16) PH2_STEP(a4.y, 17) PH2_STEP(a4.z, 18) PH2_STEP(a4.w, 19)
                    if (iseg == 3) {
                        float a20 = A_lds[tl * AP + 80];
                        float a21 = A_lds[tl * AP + 81];
                        PH2_STEP(a20, 20) PH2_STEP(a21, 21)
                    }
#undef PH2_STEP
                    m0 = fmaxf(m0, __shfl_xor(m0, 1)); m1 = fmaxf(m1, __shfl_xor(m1, 1));
                    m2 = fmaxf(m2, __shfl_xor(m2, 1));
                    m0 = fmaxf(m0, __shfl_xor(m0, 2)); m1 = fmaxf(m1, __shfl_xor(m1, 2));
                    m2 = fmaxf(m2, __shfl_xor(m2, 2));
                    // lanes 0..2 of the quad each write one j (cols 82/83 = pad, harmless)
                    if (iseg == 0) fb[tl * AP + j0]     = m0;
                    else if (iseg == 1) fb[tl * AP + j0 + 1] = m1;
                    else if (iseg == 2) fb[tl * AP + j0 + 2] = m2;
                }
            }
        }

        // ---- non-reset slots: 28 unrolled sequential adds ----
#pragma unroll
        for (int q = 0; q < 4; ++q) {
            if (nrV[q]) {
                const int a = nrFo[q] + nrR[q];
                float v = V[a];
#pragma unroll
                for (int tt = 0; tt < WMAX; ++tt) v += nbr[tt];
                V[a] = v;
            }
        }
        __syncthreads();   // B2: fb ready

        // ---- suffix: entry + remaining adds (exact sequential; r3 form) ----
        {
            const float bw = win_b[buf][ro];
            float e0 = ract ? (fb[ro * AP + rb0] + bw) : 0.0f;
            float e1 = ract ? (fb[ro * AP + rb1] + bw) : 0.0f;
            float e2 = rv2  ? (fb[ro * AP + rb2] + bw) : 0.0f;
            for (int tt = ro + 1; tt < WMAX; ++tt) {
                const float w = win_nb[buf][tt];
                e0 += w; e1 += w; e2 += w;
            }
            // last chunk: resets at padded offsets (ro>=7) must not happen;
            // capture C == exact final value there (pad adds are +0.0)
            const bool keepC = (c == NCHUNK - 1) && (ro >= 7);
            if (ract) {
                V[rf0 + rr0] = keepC ? cv0 : e0;
                V[rf1 + rr1] = keepC ? cv1 : e1;
                if (rv2) V[rf2 + rr2] = keepC ? cv2 : e2;
            }
            rr0 += WMAX; if (rr0 >= rt0) rr0 -= rt0;
            rr1 += WMAX; if (rr1 >= rt1) rr1 -= rt1;
            rr2 += WMAX; if (rr2 >= rt2) rr2 -= rt2;
        }
#pragma unroll
        for (int q = 0; q < 4; ++q) {
            if (nrV[q]) { nrR[q] += WMAX; if (nrR[q] >= nrTau[q]) nrR[q] -= nrTau[q]; }
        }
        __syncthreads();   // B3: protect V writes from next chunk's prefix reads
    }

    // ---- final argmax over V (p = (5998 - r) mod tau) ----
    float bvv = -INFINITY; int bss = 0x7fffffff;
    for (int g = tid; g < S_TOT; g += NTHREADS) {
        int lo = 0, hi = NTAU - 1;
        while (lo < hi) { int mid = (lo + hi + 1) >> 1;
                          if (first_of(mid) <= g) lo = mid; else hi = mid - 1; }
        const int tau = TMIN + lo;
        const int r = g - first_of(lo);
        const int p = (5998 - r) % tau;
        const int s = first_of(lo) + p;
        const float v = V[g];
        if (v > bvv || (v == bvv && s < bss)) { bvv = v; bss = s; }
    }
#pragma unroll
    for (int d = 1; d < 64; d <<= 1) {
        float ov = __shfl_xor(bvv, d);
        int   os = __shfl_xor(bss, d);
        if (ov > bvv || (ov == bvv && os < bss)) { bvv = ov; bss = os; }
    }
    if ((tid & 63) == 0) { wv[tid >> 6] = bvv; wi[tid >> 6] = bss; }
    __syncthreads();

    __threadfence();   // Ah global writes visible before backtrace reads

    // ---- backtrace: wave 0, wave-parallel 82-wide argmax per beat boundary ----
    if (tid < 64) {
        const int lane = tid;
        float bvF = (lane < 16) ? wv[lane] : -INFINITY;
        int   bvI = (lane < 16) ? wi[lane] : 0x7fffffff;
#pragma unroll
        for (int d = 1; d < 16; d <<= 1) {
            float ov = __shfl_xor(bvF, d);
            int   os = __shfl_xor(bvI, d);
            if (ov > bvF || (ov == bvF && os < bvI)) { bvF = ov; bvI = os; }
        }
        int s = __shfl(bvI, 0);
        int t = TF - 1;
        for (int guard = 0; guard < 400; ++guard) {
            int lo = 0, hi = NTAU - 1;
            while (lo < hi) { int mid = (lo + hi + 1) >> 1;
                              if (first_of(mid) <= s) lo = mid; else hi = mid - 1; }
            int j = lo;
            int p = s - first_of(j);
            int tb = t - p;
            if (tb < 0) break;
            if (lane == 0) {
                float x = logit[b * TF + tb];
                float act = 1.0f / (1.0f + expf(-x));
                if (act >= 0.05f) out[b * TF + tb] = 1.0f;
            }
            if (tb == 0) break;
            const int tq = tb - 1;
            const float* arow = Ah + (size_t)(tq / WMAX) * CHUNK_F + (tq % WMAX) * AP;
            float cvv = arow[lane] + transg[lane * NTAU + j];
            int ci = lane;
            if (lane < NTAU - 64) {
                float c2 = arow[64 + lane] + transg[(64 + lane) * NTAU + j];
                if (c2 > cvv) { cvv = c2; ci = 64 + lane; }
            }
#pragma unroll
            for (int d = 1; d < 64; d <<= 1) {
                float ov = __shfl_xor(cvv, d, 64);
                int   oi = __shfl_xor(ci, d, 64);
                if (ov > cvv || (ov == cvv && oi < ci)) { cvv = ov; ci = oi; }
            }
            s = first_of(ci) + (TMIN + ci) - 1;   // last_idx[i*]
            t = tb - 1;
        }
    }
}

extern "C" void kernel_launch(void* const* d_in, const int* in_sizes, int n_in,
                              void* d_out, int out_size, void* d_ws, size_t ws_size,
                              hipStream_t stream) {
    const float* logit = (const float*)d_in[0];
    float* out = (float*)d_out;
    float* ws = (float*)d_ws;
    k_trans<<<dim3(NTAU), dim3(128), 0, stream>>>(ws);
    k_emis<<<dim3((BATCH * TF + 255) / 256), dim3(256), 0, stream>>>(logit, ws, out);
    k_viterbi<<<dim3(BATCH), dim3(NTHREADS), 0, stream>>>(
        logit, ws + TRANS_OFF, ws + BLP_OFF, ws + NBLP_OFF, ws + AH_OFF, out);
}

// Round 7
// 1536.306 us; speedup vs baseline: 3.9534x; 3.9534x over previous
//
#include <hip/hip_runtime.h>
#include <math.h>

#define NTAU 82
#define TMIN 28
#define S_TOT 5617
#define TF 6000
#define BATCH 4
#define WMAX 28
#define AP 84            // A/fb row pitch: 82 + 2 pad; rows 336B = 21*16B aligned
#define NTHREADS 1024
#define NCHUNK 215
#define CHUNK_F (WMAX * AP)   // 2352 floats per chunk of A-history

// ws layout (float offsets)
#define TRANS_OFF 0            // 82*82
#define BLP_OFF   8192         // 4*6000
#define NBLP_OFF  32768        // 4*6000
#define AH_OFF    57344        // 4 * 215 * 2352 (chunk-major A history)

__device__ __forceinline__ int first_of(int b) { return b * (55 + b) / 2; }
__device__ __forceinline__ int nf_of(int b)    { return b * (b - 1) / 2; }

__device__ __forceinline__ float logsig(float x) {
    return -(fmaxf(-x, 0.0f) + log1pf(expf(-fabsf(x))));
}

// ---------------- setup kernel 1: trans_log in fp64, cast to fp32 -------------
__global__ void k_trans(float* __restrict__ ws) {
    int i = blockIdx.x;
    int j = threadIdx.x;
    __shared__ double sh[128];
    double raw = 0.0, e = 0.0;
    double ti = 28.0 + (double)i;
    if (j < NTAU) {
        double tj = 28.0 + (double)j;
        raw = -100.0 * fabs(tj / ti - 1.0);
        e = exp(raw);
    }
    sh[j] = e;
    __syncthreads();
    for (int st = 64; st > 0; st >>= 1) {
        if (j < st) sh[j] += sh[j + st];
        __syncthreads();
    }
    double lse = log(sh[0]);
    if (j < NTAU) ws[TRANS_OFF + i * NTAU + j] = (float)(raw - lse);
}

// ---------------- setup kernel 2: emissions + zero output ---------------------
__global__ void k_emis(const float* __restrict__ logit, float* __restrict__ ws,
                       float* __restrict__ out) {
    int idx = blockIdx.x * blockDim.x + threadIdx.x;
    if (idx < BATCH * TF) {
        float x = logit[idx];
        ws[BLP_OFF + idx]  = logsig(x);
        ws[NBLP_OFF + idx] = logsig(-x);
        out[idx] = 0.0f;
    }
}

// ---------------- main kernel: chunked Viterbi + backtrace --------------------
// ONLY change vs the 1555us champion (r3): amdgpu_num_vgpr(128) — request the
// full unified budget as ARCH VGPRs so tr0/tr1/nbr stop living in AGPRs
// (every AGPR array access costs a v_accvgpr_read on the critical path).
__global__ __attribute__((amdgpu_flat_work_group_size(NTHREADS, NTHREADS),
                          amdgpu_waves_per_eu(4, 4),
                          amdgpu_num_vgpr(128)))
void k_viterbi(const float* __restrict__ logit,
               const float* __restrict__ transg,
               const float* __restrict__ blp_all,
               const float* __restrict__ nblp_all,
               float* __restrict__ Ah_all,
               float* __restrict__ out) {
    const int tid = threadIdx.x;
    const int b = blockIdx.x;

    const float* blp  = blp_all  + b * TF;
    const float* nblp = nblp_all + b * TF;
    float* Ah = Ah_all + (size_t)b * (NCHUNK * CHUNK_F);

    __shared__ float V[5632];                       // slot values, idx = first_of(b)+r
    __shared__ __align__(16) float A_lds[CHUNK_F];  // captures (prev_last) [tt][i]
    __shared__ __align__(16) float fb[CHUNK_F];     // from_beat [tt][j]
    __shared__ __align__(16) float win_nb[4][WMAX]; // quad-buffered emission windows
    __shared__ __align__(16) float win_b[4][WMAX];
    __shared__ float wv[16];
    __shared__ int   wi[16];

    // ---- ph2 mapping (r3-proven): quad lanes = iseg; jp = j-pair; tg = tl-group
    const int iseg = tid & 3;
    const int jp   = (tid >> 2) % 41;     // j-pair, j0 = 2*jp (0..80)
    const int tg   = tid / 164;           // 0..6 (quads never straddle: 164%4==0)
    const bool p2act = (tid < 984);       // 4*41*6
    const int i0 = iseg * 20;             // 20/20/20/22 split; 16B-aligned offsets
    const int j0 = jp * 2;

    // trans columns in registers: tr0/tr1[k] = trans[i0+k][j0 / j0+1]
    float tr0[22], tr1[22];
#pragma unroll
    for (int k = 0; k < 22; ++k) { tr0[k] = -1.0e30f; tr1[k] = -1.0e30f; }
    if (p2act) {
        const int icnt = (iseg == 3) ? 22 : 20;
#pragma unroll
        for (int k = 0; k < 22; ++k) {
            if (k < icnt) {
                tr0[k] = transg[(i0 + k) * NTAU + j0];
                tr1[k] = transg[(i0 + k) * NTAU + j0 + 1];
            }
        }
    }

    // ---- reset-slot mapping (r3-proven): thread = (off o, base s); blocks s,s+36,s+72
    const bool ract = (tid < 1008);
    const int ro = ract ? (tid / 36) : 27;
    const int rs = tid % 36;
    const bool rv2 = ract && (rs < 10);
    const int rb0 = rs, rb1 = rs + 36, rb2 = rs + 72;
    const int rt0 = TMIN + rb0, rt1 = TMIN + rb1, rt2 = TMIN + (rv2 ? rb2 : 0);
    const int rf0 = first_of(rb0), rf1 = first_of(rb1), rf2 = rv2 ? first_of(rb2) : 0;
    int rr0 = ro, rr1 = ro, rr2 = ro;

    // ---- non-reset mapping (r3-proven): flat f over 3321, 4 static slots ----
    int nrR[4], nrFo[4], nrTau[4];
    bool nrV[4];
#pragma unroll
    for (int q = 0; q < 4; ++q) {
        const int f = tid + q * NTHREADS;
        nrV[q] = (f < 3321);
        nrR[q] = 0; nrFo[q] = 0; nrTau[q] = 109;
        if (nrV[q]) {
            int lo = 1, hi = NTAU - 1;
            while (lo < hi) { int mid = (lo + hi + 1) >> 1;
                              if (nf_of(mid) <= f) lo = mid; else hi = mid - 1; }
            const int m = f - nf_of(lo);
            nrR[q]   = TMIN + m;
            nrFo[q]  = first_of(lo);
            nrTau[q] = TMIN + lo;
        }
    }

    // ---- V init ----
    const float logS = (float)log((double)S_TOT);
    const float b0 = blp[0], n0 = nblp[0];
    for (int g = tid; g < S_TOT; g += NTHREADS) {
        int lo = 0, hi = NTAU - 1;
        while (lo < hi) { int mid = (lo + hi + 1) >> 1;
                          if (first_of(mid) <= g) lo = mid; else hi = mid - 1; }
        const int tau = TMIN + lo;
        const int r = g - first_of(lo);
        V[g] = ((r == tau - 1) ? b0 : n0) - logS;
    }

    auto winload = [&](int cc) {
        if (cc < NCHUNK && tid < WMAX) {
            int gt = 1 + cc * WMAX + tid;
            win_nb[cc & 3][tid] = (gt < TF) ? nblp[gt] : 0.0f;
            win_b [cc & 3][tid] = (gt < TF) ? blp[gt]  : 0.0f;
        }
    };
    winload(0);
    winload(1);
    __syncthreads();

    float cv0 = 0.0f, cv1 = 0.0f, cv2 = 0.0f;
    for (int c = 0; c < NCHUNK; ++c) {
        const int buf = c & 3;

        // ---- window to registers (b128 loads; constant-index use only) ----
        float nbr[WMAX];
        {
            const float4* wn4 = (const float4*)&win_nb[buf][0];
#pragma unroll
            for (int qq = 0; qq < 7; ++qq) {
                float4 t4 = wn4[qq];
                nbr[4*qq+0] = t4.x; nbr[4*qq+1] = t4.y; nbr[4*qq+2] = t4.z; nbr[4*qq+3] = t4.w;
            }
        }

        // ---- prefix: capture C = V + nb[0..ro-1] (exact sequential) ----
        cv0 = ract ? V[rf0 + rr0] : 0.0f;
        cv1 = ract ? V[rf1 + rr1] : 0.0f;
        cv2 = rv2  ? V[rf2 + rr2] : 0.0f;
        for (int tt = 0; tt < ro; ++tt) {
            const float w = win_nb[buf][tt];
            cv0 += w; cv1 += w; cv2 += w;
        }
        if (ract) {
            A_lds[ro * AP + rb0] = cv0;
            A_lds[ro * AP + rb1] = cv1;
            if (rv2) A_lds[ro * AP + rb2] = cv2;
        }
        winload(c + 2);
        __syncthreads();   // B1: captures ready

        // ---- A history to global (coalesced float4) ----
        if (tid < CHUNK_F / 4) {
            float4 v4 = ((const float4*)A_lds)[tid];
            ((float4*)(Ah + (size_t)c * CHUNK_F))[tid] = v4;
        }

        // ---- ph2: from_beat max-plus; A rows b128; 4-lane shuffle reduce ----
        if (p2act) {
#pragma unroll
            for (int u = 0; u < 5; ++u) {
                const int tl = tg + 6 * u;
                if (tl < WMAX) {
                    const float4* ar4 = (const float4*)&A_lds[tl * AP + i0];
                    const float4 a0 = ar4[0], a1 = ar4[1], a2 = ar4[2],
                                 a3 = ar4[3], a4 = ar4[4];
                    float m0 = -INFINITY, m1 = -INFINITY;
#define PH2_STEP(av, k) \
    m0 = fmaxf(m0, (av) + tr0[k]); \
    m1 = fmaxf(m1, (av) + tr1[k]);
                    PH2_STEP(a0.x, 0)  PH2_STEP(a0.y, 1)  PH2_STEP(a0.z, 2)  PH2_STEP(a0.w, 3)
                    PH2_STEP(a1.x, 4)  PH2_STEP(a1.y, 5)  PH2_STEP(a1.z, 6)  PH2_STEP(a1.w, 7)
                    PH2_STEP(a2.x, 8)  PH2_STEP(a2.y, 9)  PH2_STEP(a2.z, 10) PH2_STEP(a2.w, 11)
                    PH2_STEP(a3.x, 12) PH2_STEP(a3.y, 13) PH2_STEP(a3.z, 14) PH2_STEP(a3.w, 15)
                    PH2_STEP(a4.x, 16) PH2_STEP(a4.y, 17) PH2_STEP(a4.z, 18) PH2_STEP(a4.w, 19)
                    if (iseg == 3) {
                        float a20 = A_lds[tl * AP + 80];
                        float a21 = A_lds[tl * AP + 81];
                        PH2_STEP(a20, 20) PH2_STEP(a21, 21)
                    }
#undef PH2_STEP
                    m0 = fmaxf(m0, __shfl_xor(m0, 1)); m1 = fmaxf(m1, __shfl_xor(m1, 1));
                    m0 = fmaxf(m0, __shfl_xor(m0, 2)); m1 = fmaxf(m1, __shfl_xor(m1, 2));
                    if (iseg == 0) *(float2*)&fb[tl * AP + j0] = make_float2(m0, m1);
                }
            }
        }

        // ---- non-reset slots: 28 unrolled sequential adds ----
#pragma unroll
        for (int q = 0; q < 4; ++q) {
            if (nrV[q]) {
                const int a = nrFo[q] + nrR[q];
                float v = V[a];
#pragma unroll
                for (int tt = 0; tt < WMAX; ++tt) v += nbr[tt];
                V[a] = v;
            }
        }
        __syncthreads();   // B2: fb ready

        // ---- suffix: entry + remaining adds (exact sequential) ----
        {
            const float bw = win_b[buf][ro];
            float e0 = ract ? (fb[ro * AP + rb0] + bw) : 0.0f;
            float e1 = ract ? (fb[ro * AP + rb1] + bw) : 0.0f;
            float e2 = rv2  ? (fb[ro * AP + rb2] + bw) : 0.0f;
            for (int tt = ro + 1; tt < WMAX; ++tt) {
                const float w = win_nb[buf][tt];
                e0 += w; e1 += w; e2 += w;
            }
            // last chunk: resets at padded offsets (ro>=7) must not happen;
            // capture C == exact final value there (pad adds are +0.0)
            const bool keepC = (c == NCHUNK - 1) && (ro >= 7);
            if (ract) {
                V[rf0 + rr0] = keepC ? cv0 : e0;
                V[rf1 + rr1] = keepC ? cv1 : e1;
                if (rv2) V[rf2 + rr2] = keepC ? cv2 : e2;
            }
            rr0 += WMAX; if (rr0 >= rt0) rr0 -= rt0;
            rr1 += WMAX; if (rr1 >= rt1) rr1 -= rt1;
            rr2 += WMAX; if (rr2 >= rt2) rr2 -= rt2;
        }
#pragma unroll
        for (int q = 0; q < 4; ++q) {
            if (nrV[q]) { nrR[q] += WMAX; if (nrR[q] >= nrTau[q]) nrR[q] -= nrTau[q]; }
        }
        __syncthreads();   // B3: protect V writes from next chunk's prefix reads
    }

    // ---- final argmax over V (p = (5998 - r) mod tau) ----
    float bvv = -INFINITY; int bss = 0x7fffffff;
    for (int g = tid; g < S_TOT; g += NTHREADS) {
        int lo = 0, hi = NTAU - 1;
        while (lo < hi) { int mid = (lo + hi + 1) >> 1;
                          if (first_of(mid) <= g) lo = mid; else hi = mid - 1; }
        const int tau = TMIN + lo;
        const int r = g - first_of(lo);
        const int p = (5998 - r) % tau;
        const int s = first_of(lo) + p;
        const float v = V[g];
        if (v > bvv || (v == bvv && s < bss)) { bvv = v; bss = s; }
    }
#pragma unroll
    for (int d = 1; d < 64; d <<= 1) {
        float ov = __shfl_xor(bvv, d);
        int   os = __shfl_xor(bss, d);
        if (ov > bvv || (ov == bvv && os < bss)) { bvv = ov; bss = os; }
    }
    if ((tid & 63) == 0) { wv[tid >> 6] = bvv; wi[tid >> 6] = bss; }
    __syncthreads();

    __threadfence();   // Ah global writes visible before backtrace reads

    // ---- backtrace: wave 0, wave-parallel 82-wide argmax per beat boundary ----
    if (tid < 64) {
        const int lane = tid;
        float bvF = (lane < 16) ? wv[lane] : -INFINITY;
        int   bvI = (lane < 16) ? wi[lane] : 0x7fffffff;
#pragma unroll
        for (int d = 1; d < 16; d <<= 1) {
            float ov = __shfl_xor(bvF, d);
            int   os = __shfl_xor(bvI, d);
            if (ov > bvF || (ov == bvF && os < bvI)) { bvF = ov; bvI = os; }
        }
        int s = __shfl(bvI, 0);
        int t = TF - 1;
        for (int guard = 0; guard < 400; ++guard) {
            int lo = 0, hi = NTAU - 1;
            while (lo < hi) { int mid = (lo + hi + 1) >> 1;
                              if (first_of(mid) <= s) lo = mid; else hi = mid - 1; }
            int j = lo;
            int p = s - first_of(j);
            int tb = t - p;
            if (tb < 0) break;
            if (lane == 0) {
                float x = logit[b * TF + tb];
                float act = 1.0f / (1.0f + expf(-x));
                if (act >= 0.05f) out[b * TF + tb] = 1.0f;
            }
            if (tb == 0) break;
            const int tq = tb - 1;
            const float* arow = Ah + (size_t)(tq / WMAX) * CHUNK_F + (tq % WMAX) * AP;
            float cvv = arow[lane] + transg[lane * NTAU + j];
            int ci = lane;
            if (lane < NTAU - 64) {
                float c2 = arow[64 + lane] + transg[(64 + lane) * NTAU + j];
                if (c2 > cvv) { cvv = c2; ci = 64 + lane; }
            }
#pragma unroll
            for (int d = 1; d < 64; d <<= 1) {
                float ov = __shfl_xor(cvv, d, 64);
                int   oi = __shfl_xor(ci, d, 64);
                if (ov > cvv || (ov == cvv && oi < ci)) { cvv = ov; ci = oi; }
            }
            s = first_of(ci) + (TMIN + ci) - 1;   // last_idx[i*]
            t = tb - 1;
        }
    }
}

extern "C" void kernel_launch(void* const* d_in, const int* in_sizes, int n_in,
                              void* d_out, int out_size, void* d_ws, size_t ws_size,
                              hipStream_t stream) {
    const float* logit = (const float*)d_in[0];
    float* out = (float*)d_out;
    float* ws = (float*)d_ws;
    k_trans<<<dim3(NTAU), dim3(128), 0, stream>>>(ws);
    k_emis<<<dim3((BATCH * TF + 255) / 256), dim3(256), 0, stream>>>(logit, ws, out);
    k_viterbi<<<dim3(BATCH), dim3(NTHREADS), 0, stream>>>(
        logit, ws + TRANS_OFF, ws + BLP_OFF, ws + NBLP_OFF, ws + AH_OFF, out);
}